// Round 2
// baseline (11556.187 us; speedup 1.0000x reference)
//
#include <hip/hip_runtime.h>
#include <hip/hip_bf16.h>

// ---------------------------------------------------------------------------
// ViTChess: 6-layer transformer block stack, B=512 N=65 C=768 H=12 DH=64
// bf16 MFMA GEMMs (32x32x16), fp32 accum, residual stream lives in d_out.
// Workspace budget ~289 MB (per-layer weight staging, bf16 bias, chunked MLP).
// ---------------------------------------------------------------------------

typedef __bf16 v8bf  __attribute__((ext_vector_type(8)));
typedef float  v16f  __attribute__((ext_vector_type(16)));

#define EPI_BF16      0
#define EPI_ADDF32    1
#define EPI_SILU      2
#define EPI_MUL       3
#define EPI_BF16MASK  4

__device__ __forceinline__ v16f mfma32(v8bf a, v8bf b, v16f c) {
  return __builtin_amdgcn_mfma_f32_32x32x16_bf16(a, b, c, 0, 0, 0);
}

// C[M,N] = A[M,K] @ Bt[N,K]^T.  M%128==0, N%128==0 (padded), K%64==0.
// LDS tiles 128x64 bf16, 16B chunks XOR-swizzled by (row&7).
template<int EPI>
__global__ __launch_bounds__(256, 3)
void gemm_bt(const __bf16* __restrict__ A, long long lda,
             const __bf16* __restrict__ Bt,
             void* outp, const __bf16* extra,
             int Nout, int K, int nvalid)
{
  __shared__ __align__(16) __bf16 Als[128 * 64];
  __shared__ __align__(16) __bf16 Bls[128 * 64];
  const int tid  = threadIdx.x;
  const int w    = tid >> 6, lane = tid & 63;
  const int m0   = blockIdx.y * 128, n0 = blockIdx.x * 128;
  const int wm   = (w & 1) * 64, wn = (w >> 1) * 64;
  const int l31  = lane & 31, l5 = lane >> 5;

  const __bf16* ag[4];
  const __bf16* bg[4];
#pragma unroll
  for (int i = 0; i < 4; ++i) {
    int li  = i * 256 + tid;
    int row = li >> 3;
    int c   = (li & 7) ^ (row & 7);           // swizzled source chunk
    ag[i] = A  + (size_t)(m0 + row) * (size_t)lda + c * 8;
    bg[i] = Bt + (size_t)(n0 + row) * (size_t)K   + c * 8;
  }
  char* alds0 = ((char*)Als) + w * 1024;
  char* blds0 = ((char*)Bls) + w * 1024;

  v16f acc[2][2] = {};

  for (int kt = 0; kt < K; kt += 64) {
#pragma unroll
    for (int i = 0; i < 4; ++i) {
      __builtin_amdgcn_global_load_lds(
          (const __attribute__((address_space(1))) void*)(ag[i]),
          (__attribute__((address_space(3))) void*)(alds0 + i * 4096), 16, 0, 0);
      __builtin_amdgcn_global_load_lds(
          (const __attribute__((address_space(1))) void*)(bg[i]),
          (__attribute__((address_space(3))) void*)(blds0 + i * 4096), 16, 0, 0);
      ag[i] += 64; bg[i] += 64;
    }
    __syncthreads();
#pragma unroll
    for (int kk = 0; kk < 4; ++kk) {
      v8bf af[2], bf[2];
#pragma unroll
      for (int t = 0; t < 2; ++t) {
        int m  = wm + t * 32 + l31;
        int ch = (kk * 2 + l5) ^ (m & 7);
        af[t] = *(const v8bf*)(Als + m * 64 + ch * 8);
        int n   = wn + t * 32 + l31;
        int ch2 = (kk * 2 + l5) ^ (n & 7);
        bf[t] = *(const v8bf*)(Bls + n * 64 + ch2 * 8);
      }
      acc[0][0] = mfma32(af[0], bf[0], acc[0][0]);
      acc[0][1] = mfma32(af[0], bf[1], acc[0][1]);
      acc[1][0] = mfma32(af[1], bf[0], acc[1][0]);
      acc[1][1] = mfma32(af[1], bf[1], acc[1][1]);
    }
    __syncthreads();
  }

  // D layout: col = lane&31, row = (r&3) + 8*(r>>2) + 4*(lane>>5)
#pragma unroll
  for (int mi = 0; mi < 2; ++mi)
#pragma unroll
  for (int ni = 0; ni < 2; ++ni) {
    int col  = n0 + wn + ni * 32 + l31;
    int rowb = m0 + wm + mi * 32 + 4 * l5;
#pragma unroll
    for (int r = 0; r < 16; ++r) {
      int row   = rowb + (r & 3) + 8 * (r >> 2);
      float val = acc[mi][ni][r];
      size_t idx = (size_t)row * (size_t)Nout + col;
      if (EPI == EPI_BF16) {
        ((__bf16*)outp)[idx] = (__bf16)val;
      } else if (EPI == EPI_ADDF32) {
        ((float*)outp)[idx] += val;
      } else if (EPI == EPI_SILU) {
        float s = val / (1.f + __expf(-val));
        ((__bf16*)outp)[idx] = (__bf16)s;
      } else if (EPI == EPI_MUL) {
        float e = (float)extra[idx];
        ((__bf16*)outp)[idx] = (__bf16)(val * e);
      } else { // EPI_BF16MASK: compacted Nout=nvalid output
        if (col < nvalid)
          ((__bf16*)outp)[(size_t)row * (size_t)nvalid + col] = (__bf16)val;
      }
    }
  }
}

// fp32 (K,N) -> bf16 (Npad,K) transpose; pad rows zero-filled.
__global__ void transpose_w(const float* __restrict__ src, __bf16* __restrict__ dst,
                            int K, int N, int Npad)
{
  __shared__ float t[32][33];
  int n0 = blockIdx.x * 32, k0 = blockIdx.y * 32;
  int tx = threadIdx.x, ty = threadIdx.y;
#pragma unroll
  for (int i = 0; i < 32; i += 8) {
    int k = k0 + ty + i, n = n0 + tx;
    t[ty + i][tx] = (k < K && n < N) ? src[(size_t)k * N + n] : 0.f;
  }
  __syncthreads();
#pragma unroll
  for (int i = 0; i < 32; i += 8) {
    int n = n0 + ty + i, k = k0 + tx;
    if (n < Npad && k < K) dst[(size_t)n * K + k] = (__bf16)t[tx][ty + i];
  }
}

// row LN: fp32 in -> bf16 out, one 256-thread block per row
__global__ __launch_bounds__(256)
void ln_f32_to_bf16(const float* __restrict__ x, const float* __restrict__ g,
                    const float* __restrict__ bb, __bf16* __restrict__ out, int C)
{
  __shared__ float sm[8];
  const float* xr = x + (size_t)blockIdx.x * C;
  float sum = 0.f, sq = 0.f;
  for (int i = threadIdx.x; i < C; i += 256) { float v = xr[i]; sum += v; sq += v * v; }
#pragma unroll
  for (int d = 1; d < 64; d <<= 1) { sum += __shfl_xor(sum, d); sq += __shfl_xor(sq, d); }
  if ((threadIdx.x & 63) == 0) { sm[threadIdx.x >> 6] = sum; sm[4 + (threadIdx.x >> 6)] = sq; }
  __syncthreads();
  sum = sm[0] + sm[1] + sm[2] + sm[3];
  sq  = sm[4] + sm[5] + sm[6] + sm[7];
  float mean = sum / C;
  float var  = sq / C - mean * mean;
  float rs   = rsqrtf(var + 1e-5f);
  __bf16* orow = out + (size_t)blockIdx.x * C;
  for (int i = threadIdx.x; i < C; i += 256)
    orow[i] = (__bf16)((xr[i] - mean) * rs * g[i] + bb[i]);
}

// row LN on bf16 input, optional silu
__global__ __launch_bounds__(256)
void ln_bf16_kernel(const __bf16* __restrict__ x, const float* __restrict__ g,
                    const float* __restrict__ bb, __bf16* __restrict__ out,
                    int C, int do_silu)
{
  __shared__ float sm[8];
  const __bf16* xr = x + (size_t)blockIdx.x * C;
  float sum = 0.f, sq = 0.f;
  for (int i = threadIdx.x; i < C; i += 256) { float v = (float)xr[i]; sum += v; sq += v * v; }
#pragma unroll
  for (int d = 1; d < 64; d <<= 1) { sum += __shfl_xor(sum, d); sq += __shfl_xor(sq, d); }
  if ((threadIdx.x & 63) == 0) { sm[threadIdx.x >> 6] = sum; sm[4 + (threadIdx.x >> 6)] = sq; }
  __syncthreads();
  sum = sm[0] + sm[1] + sm[2] + sm[3];
  sq  = sm[4] + sm[5] + sm[6] + sm[7];
  float mean = sum / C;
  float var  = sq / C - mean * mean;
  float rs   = rsqrtf(var + 1e-5f);
  __bf16* orow = out + (size_t)blockIdx.x * C;
  for (int i = threadIdx.x; i < C; i += 256) {
    float y = ((float)xr[i] - mean) * rs * g[i] + bb[i];
    if (do_silu) y = y / (1.f + __expf(-y));
    orow[i] = (__bf16)y;
  }
}

// fused attention per (b,h): q/k LN from raw qkv(B,N,3,H,DH), S=qk^T+bias,
// softmax, O=P@V -> o(B,N,H,DH)
__global__ __launch_bounds__(256)
void attn_kernel(const __bf16* __restrict__ qkv,
                 const float* __restrict__ qg, const float* __restrict__ qb,
                 const float* __restrict__ kg, const float* __restrict__ kb,
                 const __bf16* __restrict__ bias, __bf16* __restrict__ o)
{
  __shared__ __align__(16) float  qs[68 * 64];
  __shared__ __align__(16) float  ks[68 * 64];
  __shared__ __align__(16) __bf16 vs[68 * 64];
  __shared__ __align__(16) float  Ss[68 * 68];
  const int tid = threadIdx.x;
  const int bh  = blockIdx.x;
  const int b = bh / 12, h = bh % 12;
  const int w = tid >> 6, lane = tid & 63;
  // zero pad rows 65..67
  for (int e = tid; e < 3 * 64; e += 256) {
    int r = 65 + (e >> 6), d = e & 63;
    qs[r * 64 + d] = 0.f; ks[r * 64 + d] = 0.f; vs[r * 64 + d] = (__bf16)0.f;
  }
  const float qgl = qg[lane], qbl = qb[lane];
  const float kgl = kg[lane], kbl = kb[lane];
  for (int n = w; n < 65; n += 4) {
    size_t src = ((size_t)(b * 65 + n)) * 2304 + h * 64 + lane;
    float qv = (float)qkv[src];
    float kv = (float)qkv[src + 768];
    float s1 = qv, s2 = qv * qv, t1 = kv, t2 = kv * kv;
#pragma unroll
    for (int d = 1; d < 64; d <<= 1) {
      s1 += __shfl_xor(s1, d); s2 += __shfl_xor(s2, d);
      t1 += __shfl_xor(t1, d); t2 += __shfl_xor(t2, d);
    }
    float qm = s1 * 0.015625f, qva = s2 * 0.015625f - qm * qm;
    float km = t1 * 0.015625f, kva = t2 * 0.015625f - km * km;
    float qrs = rsqrtf(qva + 1e-5f), krs = rsqrtf(kva + 1e-5f);
    qs[n * 64 + lane] = ((qv - qm) * qrs * qgl + qbl) * 0.125f;
    ks[n * 64 + lane] = (kv - km) * krs * kgl + kbl;
    vs[n * 64 + lane] = qkv[src + 1536];
  }
  __syncthreads();
  const __bf16* bp = bias + (size_t)bh * 4225;
  for (int e = tid; e < 17 * 17; e += 256) {
    int i0 = (e / 17) * 4, j0 = (e % 17) * 4;
    float a[4][4] = {{0.f}};
    for (int d = 0; d < 64; d += 4) {
      float4 qv[4], kv[4];
#pragma unroll
      for (int t = 0; t < 4; ++t) {
        qv[t] = *(const float4*)&qs[(i0 + t) * 64 + d];
        kv[t] = *(const float4*)&ks[(j0 + t) * 64 + d];
      }
#pragma unroll
      for (int ii = 0; ii < 4; ++ii)
#pragma unroll
      for (int jj = 0; jj < 4; ++jj)
        a[ii][jj] += qv[ii].x * kv[jj].x + qv[ii].y * kv[jj].y +
                     qv[ii].z * kv[jj].z + qv[ii].w * kv[jj].w;
    }
#pragma unroll
    for (int ii = 0; ii < 4; ++ii)
#pragma unroll
    for (int jj = 0; jj < 4; ++jj) {
      int i = i0 + ii, j = j0 + jj;
      float sv;
      if (j < 65) { sv = a[ii][jj]; if (i < 65) sv += (float)bp[i * 65 + j]; }
      else sv = -1e30f;
      Ss[i * 68 + j] = sv;
    }
  }
  __syncthreads();
  for (int i = w; i < 65; i += 4) {
    float x1 = Ss[i * 68 + lane];
    float x2 = (lane < 4) ? Ss[i * 68 + 64 + lane] : -1e30f;
    float mx = fmaxf(x1, x2);
#pragma unroll
    for (int d = 1; d < 64; d <<= 1) mx = fmaxf(mx, __shfl_xor(mx, d));
    float e1 = __expf(x1 - mx);
    float e2 = (lane < 4) ? __expf(x2 - mx) : 0.f;
    float s = e1 + e2;
#pragma unroll
    for (int d = 1; d < 64; d <<= 1) s += __shfl_xor(s, d);
    float inv = 1.f / s;
    Ss[i * 68 + lane] = e1 * inv;
    if (lane < 4) Ss[i * 68 + 64 + lane] = e2 * inv;
  }
  __syncthreads();
  for (int e = tid; e < 17 * 16; e += 256) {
    int i0 = (e >> 4) * 4, d0 = (e & 15) * 4;
    float a[4][4] = {{0.f}};
    for (int j = 0; j < 68; ++j) {
      const __bf16* vp = &vs[j * 64 + d0];
      float v0 = (float)vp[0], v1 = (float)vp[1], v2 = (float)vp[2], v3 = (float)vp[3];
      float p0 = Ss[(i0 + 0) * 68 + j], p1 = Ss[(i0 + 1) * 68 + j];
      float p2 = Ss[(i0 + 2) * 68 + j], p3 = Ss[(i0 + 3) * 68 + j];
      a[0][0] += p0 * v0; a[0][1] += p0 * v1; a[0][2] += p0 * v2; a[0][3] += p0 * v3;
      a[1][0] += p1 * v0; a[1][1] += p1 * v1; a[1][2] += p1 * v2; a[1][3] += p1 * v3;
      a[2][0] += p2 * v0; a[2][1] += p2 * v1; a[2][2] += p2 * v2; a[2][3] += p2 * v3;
      a[3][0] += p3 * v0; a[3][1] += p3 * v1; a[3][2] += p3 * v2; a[3][3] += p3 * v3;
    }
#pragma unroll
    for (int ii = 0; ii < 4; ++ii) {
      int i = i0 + ii;
      if (i < 65) {
        size_t off = ((size_t)(b * 65 + i) * 12 + h) * 64 + d0;
        o[off + 0] = (__bf16)a[ii][0];
        o[off + 1] = (__bf16)a[ii][1];
        o[off + 2] = (__bf16)a[ii][2];
        o[off + 3] = (__bf16)a[ii][3];
      }
    }
  }
}

extern "C" void kernel_launch(void* const* d_in, const int* in_sizes, int n_in,
                              void* d_out, int out_size, void* d_ws, size_t ws_size,
                              hipStream_t stream)
{
  (void)in_sizes; (void)n_in; (void)ws_size;
  const float* x_in    = (const float*)d_in[0];
  const float* ln1_g   = (const float*)d_in[1];
  const float* ln1_b   = (const float*)d_in[2];
  const float* qkv_w   = (const float*)d_in[3];
  const float* proj_w  = (const float*)d_in[4];
  const float* qn_g    = (const float*)d_in[5];
  const float* qn_b    = (const float*)d_in[6];
  const float* kn_g    = (const float*)d_in[7];
  const float* kn_b    = (const float*)d_in[8];
  const float* sg_w1   = (const float*)d_in[9];
  const float* sg_ln1g = (const float*)d_in[10];
  const float* sg_ln1b = (const float*)d_in[11];
  const float* sg_w2   = (const float*)d_in[12];
  const float* sg_ln2g = (const float*)d_in[13];
  const float* sg_ln2b = (const float*)d_in[14];
  const float* sg_bw   = (const float*)d_in[15];
  const float* ln2_g   = (const float*)d_in[16];
  const float* ln2_b   = (const float*)d_in[17];
  const float* gate_w  = (const float*)d_in[18];
  const float* value_w = (const float*)d_in[19];
  const float* out_w   = (const float*)d_in[20];

  char* ws = (char*)d_ws;
  size_t off = 0;
  auto alloc = [&](size_t bytes) -> char* {
    char* p = ws + off; off += (bytes + 255) & ~(size_t)255; return p;
  };

  // per-layer bf16 transposed weights (~25 MB total)
  __bf16* wt_qkv  = (__bf16*)alloc(2304ull * 768 * 2);
  __bf16* wt_proj = (__bf16*)alloc(768ull * 768 * 2);
  __bf16* wt_sg1  = (__bf16*)alloc(512ull * 768 * 2);
  __bf16* wt_sg2  = (__bf16*)alloc(3072ull * 512 * 2);
  __bf16* wt_bias = (__bf16*)alloc(4352ull * 256 * 2);
  __bf16* wt_gate = (__bf16*)alloc(3072ull * 768 * 2);
  __bf16* wt_val  = (__bf16*)alloc(3072ull * 768 * 2);
  __bf16* wt_out  = (__bf16*)alloc(768ull * 3072 * 2);
  // activations
  __bf16* hbuf    = (__bf16*)alloc(33280ull * 768 * 2);   // h / o / h2  (51 MB)
  __bf16* biasbuf = (__bf16*)alloc(6144ull * 4225 * 2);   // attn bias   (52 MB)
  __bf16* BIG     = (__bf16*)alloc(33280ull * 2304 * 2);  // qkv | mlp  (153 MB)
  __bf16* t1buf   = (__bf16*)alloc(512ull * 512 * 2);
  __bf16* lat1    = (__bf16*)alloc(512ull * 512 * 2);
  __bf16* t2buf   = (__bf16*)alloc(512ull * 3072 * 2);
  __bf16* lat2    = (__bf16*)alloc(512ull * 3072 * 2);

  __bf16* qkvbuf = BIG;      // 33280 x 2304
  __bf16* mlpbuf = BIG;      // 16640 x 3072 per chunk (<= qkv region)

  hipMemcpyAsync(d_out, x_in, (size_t)out_size * sizeof(float),
                 hipMemcpyDeviceToDevice, stream);
  float* xb = (float*)d_out;

  dim3 tb(32, 8);
  for (int l = 0; l < 6; ++l) {
    const float* l1g = ln1_g + l * 768;
    const float* l1b = ln1_b + l * 768;
    const float* qg  = qn_g + l * 64;
    const float* qb  = qn_b + l * 64;
    const float* kg  = kn_g + l * 64;
    const float* kb  = kn_b + l * 64;
    const float* s1g = sg_ln1g + l * 512;
    const float* s1b = sg_ln1b + l * 512;
    const float* s2g = sg_ln2g + l * 3072;
    const float* s2b = sg_ln2b + l * 3072;
    const float* l2g = ln2_g + l * 768;
    const float* l2b = ln2_b + l * 768;

    // stage this layer's weights as bf16 N x K
    transpose_w<<<dim3(72, 24), tb, 0, stream>>>(qkv_w  + (size_t)l * 768 * 2304, wt_qkv, 768, 2304, 2304);
    transpose_w<<<dim3(24, 24), tb, 0, stream>>>(proj_w + (size_t)l * 768 * 768,  wt_proj, 768, 768, 768);
    transpose_w<<<dim3(16, 24), tb, 0, stream>>>(sg_w1  + (size_t)l * 768 * 512,  wt_sg1, 768, 512, 512);
    transpose_w<<<dim3(96, 16), tb, 0, stream>>>(sg_w2  + (size_t)l * 512 * 3072, wt_sg2, 512, 3072, 3072);
    transpose_w<<<dim3(136, 8), tb, 0, stream>>>(sg_bw  + (size_t)l * 256 * 4225, wt_bias, 256, 4225, 4352);
    transpose_w<<<dim3(96, 24), tb, 0, stream>>>(gate_w + (size_t)l * 768 * 3072, wt_gate, 768, 3072, 3072);
    transpose_w<<<dim3(96, 24), tb, 0, stream>>>(value_w+ (size_t)l * 768 * 3072, wt_val, 768, 3072, 3072);
    transpose_w<<<dim3(24, 96), tb, 0, stream>>>(out_w  + (size_t)l * 3072 * 768, wt_out, 3072, 768, 768);

    // LN1: x -> h (bf16)
    ln_f32_to_bf16<<<33280, 256, 0, stream>>>(xb, l1g, l1b, hbuf, 768);
    // qkv = h @ Wqkv  (33280 x 2304)
    gemm_bt<EPI_BF16><<<dim3(18, 260), 256, 0, stream>>>(
        hbuf, 768, wt_qkv, qkvbuf, nullptr, 2304, 768, 2304);
    // cls path: t1 = cls @ w1 (cls rows = h[b*65], lda = 65*768)
    gemm_bt<EPI_BF16><<<dim3(4, 4), 256, 0, stream>>>(
        hbuf, 65 * 768, wt_sg1, t1buf, nullptr, 512, 768, 512);
    ln_bf16_kernel<<<512, 256, 0, stream>>>(t1buf, s1g, s1b, lat1, 512, 1);
    gemm_bt<EPI_BF16><<<dim3(24, 4), 256, 0, stream>>>(
        lat1, 512, wt_sg2, t2buf, nullptr, 3072, 512, 3072);
    ln_bf16_kernel<<<512, 256, 0, stream>>>(t2buf, s2g, s2b, lat2, 3072, 0);
    // bias = lat2 (6144 x 256) @ bw^T (4352 x 256), masked to 4225 cols
    gemm_bt<EPI_BF16MASK><<<dim3(34, 48), 256, 0, stream>>>(
        lat2, 256, wt_bias, biasbuf, nullptr, 4352, 256, 4225);
    // fused attention (q/k LN inside) -> o into hbuf
    attn_kernel<<<6144, 256, 0, stream>>>(qkvbuf, qg, qb, kg, kb, biasbuf, hbuf);
    // x += o @ Wproj
    gemm_bt<EPI_ADDF32><<<dim3(6, 260), 256, 0, stream>>>(
        hbuf, 768, wt_proj, xb, nullptr, 768, 768, 768);
    // LN2: x -> h2 (reuses hbuf)
    ln_f32_to_bf16<<<33280, 256, 0, stream>>>(xb, l2g, l2b, hbuf, 768);
    // gated MLP in 2 row-chunks of 16640, vsilu/gated in-place in mlpbuf
    for (int c = 0; c < 2; ++c) {
      const __bf16* h2c = hbuf + (size_t)c * 16640 * 768;
      float* xc = xb + (size_t)c * 16640 * 768;
      gemm_bt<EPI_SILU><<<dim3(24, 130), 256, 0, stream>>>(
          h2c, 768, wt_val, mlpbuf, nullptr, 3072, 768, 3072);
      gemm_bt<EPI_MUL><<<dim3(24, 130), 256, 0, stream>>>(
          h2c, 768, wt_gate, mlpbuf, mlpbuf, 3072, 768, 3072);
      gemm_bt<EPI_ADDF32><<<dim3(6, 130), 256, 0, stream>>>(
          mlpbuf, 3072, wt_out, xc, nullptr, 768, 3072, 768);
    }
  }
}